// Round 4
// baseline (161.195 us; speedup 1.0000x reference)
//
#include <hip/hip_runtime.h>
#include <hip/hip_bf16.h>
#include <math.h>

#define NSLICE 2048
#define NH 133     // output spatial size (int(128*1+4)+1)
#define NP 144     // padded to 9 tiles of 16
#define NT 576     // 9 waves per block

// LDS: union of
//   Xs      : 128 rows x 136 bf16 (row stride 272 B)          = 34,816 B
//   scratch : 9 waves x 32 segs x 136 B (seg s = p in [4s,4s+4)) = 39,168 B
#define XROW   272
#define WSEG   136
#define WBASE  4352          // per-wave scratch bytes (32*136)
#define LDSB   39168

typedef __attribute__((ext_vector_type(8))) short bf16x8;   // 8 bf16 = 4 VGPRs
typedef __attribute__((ext_vector_type(4))) float f32x4;

__device__ __forceinline__ unsigned f2bf(float f) {
    __hip_bfloat16 h = __float2bfloat16(f);   // round-to-nearest-even
    union { __hip_bfloat16 b; unsigned short u; } c; c.b = h; return (unsigned)c.u;
}

// ---------------------------------------------------------------------------
// prep_M: combined (IDCT * mask * DCT) matrices, bf16, in workspace.
//   M[row, p] = sum_{u=0}^{127} D2[u,row] * mask[u] * D1[u,p]
// Rows >= 133 are zero padding. M1 uses rate_weights[0], M2 uses [1].
// ---------------------------------------------------------------------------
__global__ void prep_M(const float* __restrict__ rw,
                       unsigned short* __restrict__ M1,
                       unsigned short* __restrict__ M2) {
    int b   = blockIdx.x;        // 0..287
    int m   = b / NP;            // 0 -> M1 (vertical), 1 -> M2 (horizontal)
    int row = b - m * NP;        // 0..143 (output index i or j)
    int p   = threadIdx.x;       // 0..127 (input index)
    unsigned short* M = (m == 0) ? M1 : M2;

    float val = 0.0f;
    if (row < NH) {
        float r = rw[m];
        float minr = fmaxf((1.0f - 4.0f) / 128.0f, 0.0f);
        r = fminf(fmaxf(r, minr), 2.0f);
        float crop = 128.0f * r;

        const float c1  = (float)(M_PI / 256.0);   // D1 phase period 512
        const float c2  = (float)(M_PI / 266.0);   // D2 phase period 532
        const float s1n = 0.125f;                  // sqrt(2/128)
        const float s10 = 0.08838834764831844f;
        const float s2n = 0.12262786485246718f;    // sqrt(2/133)
        const float s20 = 0.08671099951921386f;

        int tp = 2 * p + 1;
        int ti = 2 * row + 1;
        float acc = 0.0f;
        for (int u = 0; u < 128; ++u) {
            float mask = fminf(fmaxf((4.0f + crop - (float)u) * 0.25f, 0.0f), 1.0f);
            int a1 = (tp * u) & 511;
            int a2 = (ti * u) % 532;
            float d1 = cosf((float)a1 * c1) * ((u == 0) ? s10 : s1n);
            float d2 = cosf((float)a2 * c2) * ((u == 0) ? s20 : s2n);
            acc = fmaf(d1 * mask, d2, acc);
        }
        val = acc;
    }
    M[row * 128 + p] = (unsigned short)f2bf(val);
}

// ---------------------------------------------------------------------------
// dct_resize: one 576-thread block (9 waves) per (b,c) slice.
// Wave w owns output COLUMNS j0..j0+15 (j0 = 16w) end-to-end:
//   stage A: Wt[j0+r][p] = sum_q X[p][q]*M2[j0+r][q] via MFMA, kept in regs
//   repack : wave-local scratch (in Xs space) converts D-layout (4-consec p)
//            into B-fragment layout (8-consec p)  -- no cross-wave exchange
//   stage B: out[i][j0+r] = sum_p M1[i][p]*Wt[j0+r][p], all 9 i-tiles,
//            M1 fragments from global (L1-hot, same addrs for all blocks)
// Only 2 barriers per block; LDS 38.3 KB -> 3 blocks/CU (27 waves).
// ---------------------------------------------------------------------------
__global__ __launch_bounds__(NT, 7) void dct_resize(
        const float* __restrict__ x,
        const unsigned short* __restrict__ M1,
        const unsigned short* __restrict__ M2,
        float* __restrict__ out) {
    __shared__ __align__(16) unsigned char lds[LDSB];

    const int tid  = threadIdx.x;
    const int w    = tid >> 6;      // wave 0..8
    const int lane = tid & 63;
    const int r    = lane & 15;     // fragment row/col index
    const int g    = lane >> 4;     // k-group 0..3

    const float* xs = x + (size_t)blockIdx.x * (128 * 128);
    float*       os = out + (size_t)blockIdx.x * (NH * NH);

    const int j0 = w * 16;          // this wave's output column tile

    // ---- preload loop-invariant M2 fragments (this wave's j-tile) ----
    bf16x8 bm2[4];
    #pragma unroll
    for (int kk = 0; kk < 4; ++kk)
        bm2[kk] = *(const bf16x8*)(M2 + (size_t)(j0 + r) * 128 + kk * 32 + g * 8);

    // ---- stage X into LDS as bf16 (coalesced float4 reads) ----
    for (int f = tid; f < 4096; f += NT) {
        int row = f >> 5;             // 0..127
        int c4  = f & 31;             // float4 column
        float4 v = ((const float4*)(xs + (size_t)row * 128))[c4];
        uint2 pkt;
        pkt.x = f2bf(v.x) | (f2bf(v.y) << 16);
        pkt.y = f2bf(v.z) | (f2bf(v.w) << 16);
        *(uint2*)(lds + row * XROW + c4 * 8) = pkt;
    }
    __syncthreads();

    // ---- Stage A: Wt[j0+r][p] in registers (packed bf16 pairs) ----
    uint2 u2[8];
    #pragma unroll
    for (int pt = 0; pt < 8; ++pt) {
        f32x4 acc = {0.f, 0.f, 0.f, 0.f};
        #pragma unroll
        for (int kk = 0; kk < 4; ++kk) {
            bf16x8 a = *(const bf16x8*)(lds + (pt * 16 + r) * XROW + kk * 64 + g * 16);
            acc = __builtin_amdgcn_mfma_f32_16x16x32_bf16(a, bm2[kk], acc, 0, 0, 0);
        }
        // lane holds Wt[j0+r][pt*16 + g*4 + q], q=0..3
        u2[pt].x = f2bf(acc[0]) | (f2bf(acc[1]) << 16);
        u2[pt].y = f2bf(acc[2]) | (f2bf(acc[3]) << 16);
    }
    __syncthreads();   // everyone done READING Xs; its space becomes scratch

    // ---- wave-local repack: seg s holds Wt[j0+r][4s .. 4s+3] ----
    unsigned char* scr = lds + w * WBASE;
    #pragma unroll
    for (int pt = 0; pt < 8; ++pt)
        *(uint2*)(scr + (pt * 4 + g) * WSEG + r * 8) = u2[pt];

    bf16x8 bfrag[4];
    #pragma unroll
    for (int kk = 0; kk < 4; ++kk) {
        // lane needs p = kk*32 + g*8 .. +7  ->  segs 8kk+2g, 8kk+2g+1
        uint2 lo = *(const uint2*)(scr + (8 * kk + 2 * g) * WSEG + r * 8);
        uint2 hi = *(const uint2*)(scr + (8 * kk + 2 * g + 1) * WSEG + r * 8);
        union { uint4 u; bf16x8 b; } cv;
        cv.u = make_uint4(lo.x, lo.y, hi.x, hi.y);
        bfrag[kk] = cv.b;
    }

    // ---- Stage B: all 9 i-tiles for this wave's columns ----
    const int j = j0 + r;
    #pragma unroll
    for (int it = 0; it < 9; ++it) {
        const int i0 = it * 16;
        f32x4 acc = {0.f, 0.f, 0.f, 0.f};
        #pragma unroll
        for (int kk = 0; kk < 4; ++kk) {
            bf16x8 a = *(const bf16x8*)(M1 + (size_t)(i0 + r) * 128 + kk * 32 + g * 8);
            acc = __builtin_amdgcn_mfma_f32_16x16x32_bf16(a, bfrag[kk], acc, 0, 0, 0);
        }
        if (j < NH) {
            #pragma unroll
            for (int q = 0; q < 4; ++q) {
                const int i = i0 + g * 4 + q;
                if (i < NH) os[(size_t)i * NH + j] = acc[q];
            }
        }
    }
}

extern "C" void kernel_launch(void* const* d_in, const int* in_sizes, int n_in,
                              void* d_out, int out_size, void* d_ws, size_t ws_size,
                              hipStream_t stream) {
    const float* x  = (const float*)d_in[0];
    const float* rw = (const float*)d_in[1];
    float* outp = (float*)d_out;
    unsigned short* M1 = (unsigned short*)d_ws;     // 144*128 bf16
    unsigned short* M2 = M1 + NP * 128;             // 144*128 bf16 (73.7 KB total)

    prep_M<<<dim3(2 * NP), dim3(128), 0, stream>>>(rw, M1, M2);
    dct_resize<<<dim3(NSLICE), dim3(NT), 0, stream>>>(x, M1, M2, outp);
}

// Round 5
// 145.851 us; speedup vs baseline: 1.1052x; 1.1052x over previous
//
#include <hip/hip_runtime.h>
#include <hip/hip_bf16.h>
#include <math.h>

#define NSLICE 2048
#define NH 133     // output spatial size (int(128*1+4)+1)
#define NP 144     // padded to 9 tiles of 16
#define NT 576     // 9 waves per block
#define SPB 4      // slices per block (persistent: 512 blocks = 2/CU exactly)
#define NBLK (NSLICE / SPB)

typedef __attribute__((ext_vector_type(8))) short bf16x8;   // 8 bf16 = 4 VGPRs
typedef __attribute__((ext_vector_type(4))) float f32x4;

__device__ __forceinline__ unsigned f2bf(float f) {
    __hip_bfloat16 h = __float2bfloat16(f);   // round-to-nearest-even
    union { __hip_bfloat16 b; unsigned short u; } c; c.b = h; return (unsigned)c.u;
}

// ---------------------------------------------------------------------------
// prep_M: combined (IDCT * mask * DCT) matrices, bf16, in workspace.
//   M[row, p] = sum_{u=0}^{127} D2[u,row] * mask[u] * D1[u,p]
// Rows >= 133 are zero padding. M1 uses rate_weights[0], M2 uses [1].
// ---------------------------------------------------------------------------
__global__ void prep_M(const float* __restrict__ rw,
                       unsigned short* __restrict__ M1,
                       unsigned short* __restrict__ M2) {
    int b   = blockIdx.x;        // 0..287
    int m   = b / NP;            // 0 -> M1 (vertical), 1 -> M2 (horizontal)
    int row = b - m * NP;        // 0..143 (output index i or j)
    int p   = threadIdx.x;       // 0..127 (input index)
    unsigned short* M = (m == 0) ? M1 : M2;

    float val = 0.0f;
    if (row < NH) {
        float r = rw[m];
        float minr = fmaxf((1.0f - 4.0f) / 128.0f, 0.0f);
        r = fminf(fmaxf(r, minr), 2.0f);
        float crop = 128.0f * r;

        const float c1  = (float)(M_PI / 256.0);   // D1 phase period 512
        const float c2  = (float)(M_PI / 266.0);   // D2 phase period 532
        const float s1n = 0.125f;                  // sqrt(2/128)
        const float s10 = 0.08838834764831844f;
        const float s2n = 0.12262786485246718f;    // sqrt(2/133)
        const float s20 = 0.08671099951921386f;

        int tp = 2 * p + 1;
        int ti = 2 * row + 1;
        float acc = 0.0f;
        for (int u = 0; u < 128; ++u) {
            float mask = fminf(fmaxf((4.0f + crop - (float)u) * 0.25f, 0.0f), 1.0f);
            int a1 = (tp * u) & 511;
            int a2 = (ti * u) % 532;
            float d1 = cosf((float)a1 * c1) * ((u == 0) ? s10 : s1n);
            float d2 = cosf((float)a2 * c2) * ((u == 0) ? s20 : s2n);
            acc = fmaf(d1 * mask, d2, acc);
        }
        val = acc;
    }
    M[row * 128 + p] = (unsigned short)f2bf(val);
}

// ---------------------------------------------------------------------------
// dct_resize: 512 persistent blocks (2/CU), 9 waves each, SPB slices/block.
// Round-3 dataflow (both matrix operands reg-resident, loaded once/block):
//   Stage A: wave w owns j-tile w: Tt[j0+r][p] = sum_q X[p][q]*M2[j0+r][q]
//   Stage B: wave w owns i-tile w: out[i0.., j]  = sum_p M1[i][p]*Tt[j][p]
// Pipelined: next slice's X is global_load'ed into regs at the top of
// stage A (latency hidden under A+B), converted+written to Xs after stage B.
// ---------------------------------------------------------------------------
__global__ __launch_bounds__(NT, 5) void dct_resize(
        const float* __restrict__ x,
        const unsigned short* __restrict__ M1,
        const unsigned short* __restrict__ M2,
        float* __restrict__ out) {
    __shared__ unsigned short Xs[128][136];   // 34.0 KB, row stride 17x16B
    __shared__ unsigned short Tt[144][136];   // 38.3 KB, row stride 17x16B

    const int tid  = threadIdx.x;
    const int w    = tid >> 6;      // wave 0..8
    const int lane = tid & 63;
    const int r    = lane & 15;     // fragment row/col index
    const int g    = lane >> 4;     // k-group 0..3

    const float* xbase = x   + (size_t)blockIdx.x * SPB * (128 * 128);
    float*       obase = out + (size_t)blockIdx.x * SPB * (NH * NH);

    const int j0 = w * 16;          // stage A: this wave's j-tile
    const int i0 = w * 16;          // stage B: this wave's i-tile

    // ---- preload loop-invariant matrix fragments (once per block) ----
    bf16x8 bm2[4], am1[4];
    #pragma unroll
    for (int kk = 0; kk < 4; ++kk) {
        bm2[kk] = *(const bf16x8*)(M2 + (size_t)(j0 + r) * 128 + kk * 32 + g * 8);
        am1[kk] = *(const bf16x8*)(M1 + (size_t)(i0 + r) * 128 + kk * 32 + g * 8);
    }

    // ---- prologue: stage slice 0 into Xs (waves 0-7 only: 512x8 float4) ----
    float4 xv[8];
    if (tid < 512) {
        #pragma unroll
        for (int k = 0; k < 8; ++k)
            xv[k] = ((const float4*)xbase)[tid + k * 512];
        #pragma unroll
        for (int k = 0; k < 8; ++k) {
            const int f = tid + k * 512;     // f>>5 = row, f&31 = float4 col
            uint2 pkt;
            pkt.x = f2bf(xv[k].x) | (f2bf(xv[k].y) << 16);
            pkt.y = f2bf(xv[k].z) | (f2bf(xv[k].w) << 16);
            *(uint2*)&Xs[f >> 5][(f & 31) * 4] = pkt;
        }
    }
    __syncthreads();

    for (int s = 0; s < SPB; ++s) {
        // ---- issue next slice's loads (latency hidden under stages A+B) ----
        if (s + 1 < SPB && tid < 512) {
            const float4* nx = (const float4*)(xbase + (size_t)(s + 1) * (128 * 128));
            #pragma unroll
            for (int k = 0; k < 8; ++k)
                xv[k] = nx[tid + k * 512];
        }

        // ---- Stage A: Tt[j][p] = sum_q X[p][q] * M2[j][q] ----
        #pragma unroll
        for (int pt = 0; pt < 8; ++pt) {
            f32x4 acc = {0.f, 0.f, 0.f, 0.f};
            #pragma unroll
            for (int kk = 0; kk < 4; ++kk) {
                bf16x8 a = *(const bf16x8*)&Xs[pt * 16 + r][kk * 32 + g * 8];
                acc = __builtin_amdgcn_mfma_f32_16x16x32_bf16(a, bm2[kk], acc, 0, 0, 0);
            }
            // D layout: col j = r, row p = g*4+q
            uint2 pkt;
            pkt.x = f2bf(acc[0]) | (f2bf(acc[1]) << 16);
            pkt.y = f2bf(acc[2]) | (f2bf(acc[3]) << 16);
            *(uint2*)&Tt[j0 + r][pt * 16 + g * 4] = pkt;
        }
        __syncthreads();   // Tt ready; Xs free for overwrite

        // ---- Stage B: out[i][j] = sum_p M1[i][p] * Tt[j][p] ----
        float* os = obase + (size_t)s * (NH * NH);
        #pragma unroll
        for (int jt = 0; jt < 9; ++jt) {
            f32x4 acc = {0.f, 0.f, 0.f, 0.f};
            #pragma unroll
            for (int kk = 0; kk < 4; ++kk) {
                bf16x8 b = *(const bf16x8*)&Tt[jt * 16 + r][kk * 32 + g * 8];
                acc = __builtin_amdgcn_mfma_f32_16x16x32_bf16(am1[kk], b, acc, 0, 0, 0);
            }
            const int j = jt * 16 + r;
            if (j < NH) {
                #pragma unroll
                for (int q = 0; q < 4; ++q) {
                    const int i = i0 + g * 4 + q;
                    if (i < NH) os[(size_t)i * NH + j] = acc[q];
                }
            }
        }

        // ---- write prefetched slice into Xs (vmcnt wait auto-inserted) ----
        if (s + 1 < SPB && tid < 512) {
            #pragma unroll
            for (int k = 0; k < 8; ++k) {
                const int f = tid + k * 512;
                uint2 pkt;
                pkt.x = f2bf(xv[k].x) | (f2bf(xv[k].y) << 16);
                pkt.y = f2bf(xv[k].z) | (f2bf(xv[k].w) << 16);
                *(uint2*)&Xs[f >> 5][(f & 31) * 4] = pkt;
            }
        }
        __syncthreads();
    }
}

extern "C" void kernel_launch(void* const* d_in, const int* in_sizes, int n_in,
                              void* d_out, int out_size, void* d_ws, size_t ws_size,
                              hipStream_t stream) {
    const float* x  = (const float*)d_in[0];
    const float* rw = (const float*)d_in[1];
    float* outp = (float*)d_out;
    unsigned short* M1 = (unsigned short*)d_ws;     // 144*128 bf16
    unsigned short* M2 = M1 + NP * 128;             // 144*128 bf16 (73.7 KB total)

    prep_M<<<dim3(2 * NP), dim3(128), 0, stream>>>(rw, M1, M2);
    dct_resize<<<dim3(NBLK), dim3(NT), 0, stream>>>(x, M1, M2, outp);
}

// Round 6
// 101.526 us; speedup vs baseline: 1.5877x; 1.4366x over previous
//
#include <hip/hip_runtime.h>
#include <hip/hip_bf16.h>
#include <math.h>

#define NSLICE 2048
#define NH 133     // output spatial size (int(128*1+4)+1)
#define NP 144     // padded to 9 tiles of 16
#define NT 576     // 9 waves per block

// Swizzled LDS: row stride 256 B (128 bf16, no pad); XOR bits 4-6 with row&7.
// All accesses (8B/16B, col multiple of 8/16) keep alignment; fragment reads
// hit 8 distinct 16B bank-slots per 8-lane phase -> conflict-free.
#define XSW(row, colb) ((row) * 256 + ((colb) ^ (((row) & 7) << 4)))
#define TTBASE 32768                   // Xs: 0..32767, Tt: 32768..69631
#define LDSB   69632

typedef __attribute__((ext_vector_type(8))) short bf16x8;   // 8 bf16 = 4 VGPRs
typedef __attribute__((ext_vector_type(4))) float f32x4;

__device__ __forceinline__ unsigned f2bf(float f) {
    __hip_bfloat16 h = __float2bfloat16(f);   // round-to-nearest-even
    union { __hip_bfloat16 b; unsigned short u; } c; c.b = h; return (unsigned)c.u;
}

// ---------------------------------------------------------------------------
// prep_M: combined (IDCT * mask * DCT) matrices, bf16, in workspace.
//   M[row, p] = sum_{u=0}^{127} D2[u,row] * mask[u] * D1[u,p]
// Rows >= 133 are zero padding. M1 uses rate_weights[0], M2 uses [1].
// ---------------------------------------------------------------------------
__global__ void prep_M(const float* __restrict__ rw,
                       unsigned short* __restrict__ M1,
                       unsigned short* __restrict__ M2) {
    int b   = blockIdx.x;        // 0..287
    int m   = b / NP;            // 0 -> M1 (vertical), 1 -> M2 (horizontal)
    int row = b - m * NP;        // 0..143 (output index i or j)
    int p   = threadIdx.x;       // 0..127 (input index)
    unsigned short* M = (m == 0) ? M1 : M2;

    float val = 0.0f;
    if (row < NH) {
        float r = rw[m];
        float minr = fmaxf((1.0f - 4.0f) / 128.0f, 0.0f);
        r = fminf(fmaxf(r, minr), 2.0f);
        float crop = 128.0f * r;

        const float c1  = (float)(M_PI / 256.0);   // D1 phase period 512
        const float c2  = (float)(M_PI / 266.0);   // D2 phase period 532
        const float s1n = 0.125f;                  // sqrt(2/128)
        const float s10 = 0.08838834764831844f;
        const float s2n = 0.12262786485246718f;    // sqrt(2/133)
        const float s20 = 0.08671099951921386f;

        int tp = 2 * p + 1;
        int ti = 2 * row + 1;
        float acc = 0.0f;
        for (int u = 0; u < 128; ++u) {
            float mask = fminf(fmaxf((4.0f + crop - (float)u) * 0.25f, 0.0f), 1.0f);
            int a1 = (tp * u) & 511;
            int a2 = (ti * u) % 532;
            float d1 = cosf((float)a1 * c1) * ((u == 0) ? s10 : s1n);
            float d2 = cosf((float)a2 * c2) * ((u == 0) ? s20 : s2n);
            acc = fmaf(d1 * mask, d2, acc);
        }
        val = acc;
    }
    M[row * 128 + p] = (unsigned short)f2bf(val);
}

// ---------------------------------------------------------------------------
// dct_resize: one 576-thread block (9 waves) per (b,c) slice.
//   - bm2/am1 fragments loaded ONCE per block into registers
//   - staging: 512 threads x 8 float4, loads batch-issued (sched_barrier
//     prevents the compiler sinking them), one HBM round trip per block
//   - Stage A: wave w owns j-tile w: Tt[j][p] = sum_q X[p][q]*M2[j][q]
//   - Stage B: wave w owns i-tile w: out[i][j] = sum_p M1[i][p]*Tt[j][p]
//   - LDS fully XOR-swizzled, conflict-free, 68 KB -> 2 blocks/CU
// ---------------------------------------------------------------------------
__global__ __launch_bounds__(NT, 5) void dct_resize(
        const float* __restrict__ x,
        const unsigned short* __restrict__ M1,
        const unsigned short* __restrict__ M2,
        float* __restrict__ out) {
    __shared__ __align__(16) unsigned char lds[LDSB];

    const int tid  = threadIdx.x;
    const int w    = tid >> 6;      // wave 0..8
    const int lane = tid & 63;
    const int r    = lane & 15;     // fragment row/col index
    const int g    = lane >> 4;     // k-group 0..3

    const float* xs = x + (size_t)blockIdx.x * (128 * 128);
    float*       os = out + (size_t)blockIdx.x * (NH * NH);

    const int j0 = w * 16;          // stage A: this wave's j-tile
    const int i0 = w * 16;          // stage B: this wave's i-tile

    // ---- preload loop-invariant matrix fragments (once per block) ----
    bf16x8 bm2[4], am1[4];
    #pragma unroll
    for (int kk = 0; kk < 4; ++kk) {
        bm2[kk] = *(const bf16x8*)(M2 + (size_t)(j0 + r) * 128 + kk * 32 + g * 8);
        am1[kk] = *(const bf16x8*)(M1 + (size_t)(i0 + r) * 128 + kk * 32 + g * 8);
    }

    // ---- stage X: batch-issue 8 float4 loads, then convert+write to LDS ----
    float4 xv[8];
    if (tid < 512) {
        const float4* xp = (const float4*)xs;
        #pragma unroll
        for (int k = 0; k < 8; ++k) xv[k] = xp[tid + k * 512];
    }
    __builtin_amdgcn_sched_barrier(0);   // loads may NOT sink below this
    if (tid < 512) {
        #pragma unroll
        for (int k = 0; k < 8; ++k) {
            const int f   = tid + k * 512;   // float4 index: row = f>>5, col = f&31
            const int row = f >> 5;
            const int cb  = (f & 31) * 8;    // byte column of this uint2
            uint2 pkt;
            pkt.x = f2bf(xv[k].x) | (f2bf(xv[k].y) << 16);
            pkt.y = f2bf(xv[k].z) | (f2bf(xv[k].w) << 16);
            *(uint2*)(lds + XSW(row, cb)) = pkt;
        }
    }
    __syncthreads();

    // ---- Stage A: Tt[j][p] = sum_q X[p][q] * M2[j][q] ----
    #pragma unroll
    for (int pt = 0; pt < 8; ++pt) {
        f32x4 acc = {0.f, 0.f, 0.f, 0.f};
        #pragma unroll
        for (int kk = 0; kk < 4; ++kk) {
            bf16x8 a = *(const bf16x8*)(lds + XSW(pt * 16 + r, kk * 64 + g * 16));
            acc = __builtin_amdgcn_mfma_f32_16x16x32_bf16(a, bm2[kk], acc, 0, 0, 0);
        }
        // D layout: col j = r, row p = g*4+q -> Tt[j0+r][pt*16+g*4 .. +3]
        uint2 pkt;
        pkt.x = f2bf(acc[0]) | (f2bf(acc[1]) << 16);
        pkt.y = f2bf(acc[2]) | (f2bf(acc[3]) << 16);
        *(uint2*)(lds + TTBASE + XSW(j0 + r, pt * 32 + g * 8)) = pkt;
    }
    __syncthreads();

    // ---- Stage B: out[i][j] = sum_p M1[i][p] * Tt[j][p] ----
    #pragma unroll
    for (int jt = 0; jt < 9; ++jt) {
        f32x4 acc = {0.f, 0.f, 0.f, 0.f};
        #pragma unroll
        for (int kk = 0; kk < 4; ++kk) {
            bf16x8 b = *(const bf16x8*)(lds + TTBASE + XSW(jt * 16 + r, kk * 64 + g * 16));
            acc = __builtin_amdgcn_mfma_f32_16x16x32_bf16(am1[kk], b, acc, 0, 0, 0);
        }
        const int j = jt * 16 + r;
        if (j < NH) {
            #pragma unroll
            for (int q = 0; q < 4; ++q) {
                const int i = i0 + g * 4 + q;
                if (i < NH) os[(size_t)i * NH + j] = acc[q];
            }
        }
    }
}

extern "C" void kernel_launch(void* const* d_in, const int* in_sizes, int n_in,
                              void* d_out, int out_size, void* d_ws, size_t ws_size,
                              hipStream_t stream) {
    const float* x  = (const float*)d_in[0];
    const float* rw = (const float*)d_in[1];
    float* outp = (float*)d_out;
    unsigned short* M1 = (unsigned short*)d_ws;     // 144*128 bf16
    unsigned short* M2 = M1 + NP * 128;             // 144*128 bf16 (73.7 KB total)

    prep_M<<<dim3(2 * NP), dim3(128), 0, stream>>>(rw, M1, M2);
    dct_resize<<<dim3(NSLICE), dim3(NT), 0, stream>>>(x, M1, M2, outp);
}